// Round 7
// baseline (277.914 us; speedup 1.0000x reference)
//
#include <hip/hip_runtime.h>
#include <hip/hip_bf16.h>
#include <math.h>

#define NN 16384
#define DEG 20
#define EE (NN*DEG)
#define RMAXF 3.5f
#define NG 8   // edge-groups (of 16) per block

typedef __attribute__((ext_vector_type(8))) short short8;
typedef __attribute__((ext_vector_type(4))) float f32x4;

// soft_unit_step: exp(-1/x) for x>0 else 0
__device__ __forceinline__ float su_f(float x) {
    return x > 0.0f ? __expf(-1.0f / x) : 0.0f;
}
__device__ __forceinline__ ushort f2bf(float x) {
    __hip_bfloat16 h = __float2bfloat16(x);
    return *reinterpret_cast<ushort*>(&h);
}

// ---------------------------------------------------------------------------
// prep_kernel: blocks 0..15 pack W2 B-fragments (proven); blocks 16.. compute
// per-node logit vectors mq (proven round 6):
//   mq[n][j]       = sum_i qs_i * Wd_s[i][j]               (j<8)
//   mq[n][8+3j+c]  = (sum_i qv_i[c] * Wd_v[i][j]) / sqrt3
// ---------------------------------------------------------------------------
__global__ __launch_bounds__(256) void prep_kernel(
    const float* __restrict__ f, const float* __restrict__ Wqs,
    const float* __restrict__ Wqv, const float* __restrict__ Wk2,
    const float* __restrict__ Wv2, const float* __restrict__ Wds,
    const float* __restrict__ Wdv, uint4* __restrict__ wsB2,
    float* __restrict__ mq)
{
    if (blockIdx.x < 16) {
        int tid = blockIdx.x * 256 + threadIdx.x;
        int net = tid >> 11, s = (tid >> 10) & 1, tt = (tid >> 6) & 15, lane = tid & 63;
        int qq = lane >> 4, n = lane & 15, col = tt * 16 + n;
        const float* W2 = net ? Wv2 : Wk2;
        unsigned int r[4];
        #pragma unroll
        for (int jj = 0; jj < 4; jj++) {
            int k0 = s * 32 + qq * 8 + 2 * jj;
            unsigned int lo = f2bf(W2[k0 * 256 + col] * 0.125f);
            unsigned int hi = f2bf(W2[(k0 + 1) * 256 + col] * 0.125f);
            r[jj] = lo | (hi << 16);
        }
        wsB2[tid] = make_uint4(r[0], r[1], r[2], r[3]);
    } else {
        int gid = (blockIdx.x - 16) * 256 + threadIdx.x;
        int nn = gid >> 5, idx = gid & 31;
        const float* fr = f + (size_t)nn * 32;
        const float inv8 = 0.35355339059327373f; // 1/sqrt(8)
        float out = 0.0f;
        if (idx < 8) {
            int j = idx;
            #pragma unroll
            for (int i = 0; i < 8; i++) {
                float qs = 0.0f;
                #pragma unroll
                for (int a = 0; a < 8; a++) qs = fmaf(fr[a], Wqs[a * 8 + i], qs);
                out = fmaf(qs * inv8, Wds[i * 8 + j], out);
            }
        } else {
            int kk = idx - 8;
            int j = kk / 3, c = kk - 3 * j;
            #pragma unroll
            for (int i = 0; i < 8; i++) {
                float qv = 0.0f;
                #pragma unroll
                for (int a = 0; a < 8; a++) qv = fmaf(fr[8 + 3 * a + c], Wqv[a * 8 + i], qv);
                out = fmaf(qv * inv8, Wdv[i * 8 + j], out);
            }
            out *= 0.5773502691896258f; // 1/sqrt(3)
        }
        mq[(size_t)nn * 32 + idx] = out;
    }
}

// ---------------------------------------------------------------------------
// edge_kernel: round-6 math verbatim; structural changes only:
//  - cross-group register prefetch of f/mq/pos gathers (latency overlap)
//  - double-buffered gather LDS (s_g/s_mq/s_emb/s_s1) -> 3 barriers/group
//  - stride-33 padding on s_g/s_mq (conflict-free phase-D reads)
//  - NG=8 groups per block
// ---------------------------------------------------------------------------
__global__ __launch_bounds__(256, 3) void edge_kernel(
    const float* __restrict__ f,   const float* __restrict__ pos,
    const float* __restrict__ Wk1, const float* __restrict__ Wv1,
    const int* __restrict__ esrc,  const int* __restrict__ edst,
    const float* __restrict__ mq,  const uint4* __restrict__ wsB2,
    float* __restrict__ logits, float* __restrict__ cutoff,
    float* __restrict__ vout)
{
    __shared__ float  s_w[2][16][261];                // 33.4 KB, D matrices (k,v)
    __shared__ __align__(16) ushort s_hb[2][16][64];  // 4 KB bf16 h, XOR-swizzled
    __shared__ float s_g[2][16][33];                  // 4.1 KB, f[src], dbuf, pad 33
    __shared__ float s_mq[2][16][33];                 // 4.1 KB, mq[dst], dbuf
    __shared__ float s_emb[2][16][12];                // 1.5 KB
    __shared__ float s_s1[2][16][4];                  // 0.5 KB

    const int t = threadIdx.x;
    const int wave = t >> 6, lane = t & 63;
    const int qd = lane >> 4, n = lane & 15;
    const int el16 = t >> 4, j16 = t & 15;
    const bool geo = (j16 == 0);          // 16 geometry threads, 4 per wave
    const int e0 = blockIdx.x * (16 * NG);

    // ---- loop-invariant: B fragments for this wave's 4 tiles, both nets ----
    short8 breg[2][2][4]; // [net][kstep][jj]
    #pragma unroll
    for (int net = 0; net < 2; net++)
        #pragma unroll
        for (int s = 0; s < 2; s++)
            #pragma unroll
            for (int jj = 0; jj < 4; jj++)
                breg[net][s][jj] = *(const short8*)&wsB2[net * 2048 + s * 1024 +
                                                         (wave * 4 + jj) * 64 + lane];

    // ---- prologue: prefetch group 0 gathers into registers ----
    float pf_f0, pf_f1, pf_m0, pf_m1;
    float pf_ps0 = 0, pf_ps1 = 0, pf_ps2 = 0, pf_pd0 = 0, pf_pd1 = 0, pf_pd2 = 0;
    {
        int e = e0 + el16;
        int s = esrc[e], d = edst[e];
        pf_f0 = f[(size_t)s * 32 + j16];
        pf_f1 = f[(size_t)s * 32 + 16 + j16];
        pf_m0 = mq[(size_t)d * 32 + j16];
        pf_m1 = mq[(size_t)d * 32 + 16 + j16];
        if (geo) {
            pf_ps0 = pos[s * 3 + 0]; pf_ps1 = pos[s * 3 + 1]; pf_ps2 = pos[s * 3 + 2];
            pf_pd0 = pos[d * 3 + 0]; pf_pd1 = pos[d * 3 + 1]; pf_pd2 = pos[d * 3 + 2];
        }
    }

    for (int g = 0; g < NG; g++) {
        const int p = g & 1;
        const int eg = e0 + g * 16;

        // ---- commit prefetched gathers to LDS + geometry/basis ----
        s_g[p][el16][j16]       = pf_f0;
        s_g[p][el16][16 + j16]  = pf_f1;
        s_mq[p][el16][j16]      = pf_m0;
        s_mq[p][el16][16 + j16] = pf_m1;
        if (geo) {
            float vx = pf_ps0 - pf_pd0, vy = pf_ps1 - pf_pd1, vz = pf_ps2 - pf_pd2;
            float r = sqrtf(vx * vx + vy * vy + vz * vz);
            float invr = 1.0f / r;
            const float sqrt3 = 1.7320508075688772f;
            s_s1[p][el16][0] = sqrt3 * vx * invr;
            s_s1[p][el16][1] = sqrt3 * vy * invr;
            s_s1[p][el16][2] = sqrt3 * vz * invr;
            cutoff[eg + el16] = su_f(10.0f * (1.0f - r / RMAXF));
            const float step = RMAXF / 11.0f;
            const float invstep = 11.0f / RMAXF;
            const float K = 26.66929988626f; // 1.14136*e^2*sqrt(10)
            #pragma unroll
            for (int j = 0; j < 10; j++) {
                float dd = (r - step * (float)(j + 1)) * invstep;
                s_emb[p][el16][j] = K * su_f(dd + 1.0f) * su_f(1.0f - dd);
            }
        }
        __syncthreads(); // barrier 1: gather LDS ready

        // ---- issue prefetch for group g+1 (overlaps phases B-D) ----
        if (g + 1 < NG) {
            int e = eg + 16 + el16;
            int s = esrc[e], d = edst[e];
            pf_f0 = f[(size_t)s * 32 + j16];
            pf_f1 = f[(size_t)s * 32 + 16 + j16];
            pf_m0 = mq[(size_t)d * 32 + j16];
            pf_m1 = mq[(size_t)d * 32 + 16 + j16];
            if (geo) {
                pf_ps0 = pos[s * 3 + 0]; pf_ps1 = pos[s * 3 + 1]; pf_ps2 = pos[s * 3 + 2];
                pf_pd0 = pos[d * 3 + 0]; pf_pd1 = pos[d * 3 + 1]; pf_pd2 = pos[d * 3 + 2];
            }
        }

        // ---- phase B: scalar GEMM1 + silu -> s_hb (bf16, swizzled) ----
        {
            const float invsq10 = 0.31622776601683794f; // 1/sqrt(10)
            #pragma unroll
            for (int e = 0; e < 4; e++) {
                int el = wave * 4 + e;
                float ak = 0.0f, av = 0.0f;
                #pragma unroll
                for (int j = 0; j < 10; j++) {
                    float ej = s_emb[p][el][j];
                    ak = fmaf(ej, Wk1[j * 64 + lane], ak);
                    av = fmaf(ej, Wv1[j * 64 + lane], av);
                }
                ak *= invsq10; av *= invsq10;
                float hk = ak / (1.0f + __expf(-ak));
                float hv = av / (1.0f + __expf(-av));
                int pos_ = ((((lane >> 3) ^ (el & 7))) << 3) | (lane & 7);
                s_hb[0][el][pos_] = f2bf(hk);
                s_hb[1][el][pos_] = f2bf(hv);
            }
        }
        __syncthreads(); // barrier 2

        // ---- phase C: MFMA GEMM2 for both nets -> s_w[net] ----
        #pragma unroll
        for (int net = 0; net < 2; net++) {
            short8 ha0 = *(const short8*)&s_hb[net][n][((qd ^ (n & 7)) << 3)];
            short8 ha1 = *(const short8*)&s_hb[net][n][(((4 + qd) ^ (n & 7)) << 3)];
            #pragma unroll
            for (int jj = 0; jj < 4; jj++) {
                int tt = wave * 4 + jj;
                f32x4 d = {0.0f, 0.0f, 0.0f, 0.0f};
                d = __builtin_amdgcn_mfma_f32_16x16x32_bf16(ha0, breg[net][0][jj], d, 0, 0, 0);
                d = __builtin_amdgcn_mfma_f32_16x16x32_bf16(ha1, breg[net][1][jj], d, 0, 0, 0);
                #pragma unroll
                for (int r = 0; r < 4; r++)
                    s_w[net][4 * qd + r][tt * 16 + n] = d[r]; // D: row=4*quad+reg, col=n
            }
        }
        __syncthreads(); // barrier 3

        // ---- phase D: k-net TP + mq-logits; v-net TP -> vout (round-6 math) ----
        {
            int el = el16, role = j16;
            int e = eg + el;
            float s1x = s_s1[p][el][0], s1y = s_s1[p][el][1], s1z = s_s1[p][el][2];
            const float inv_sqrt3 = 0.5773502691896258f;
            float a[8], b[8];
            #pragma unroll
            for (int i = 0; i < 8; i++) {
                a[i] = s_g[p][el][i];
                b[i] = (s_g[p][el][8 + i * 3 + 0] * s1x +
                        s_g[p][el][8 + i * 3 + 1] * s1y +
                        s_g[p][el][8 + i * 3 + 2] * s1z) * inv_sqrt3;
            }
            const float nrm = 0.25f; // 1/(sqrt(8)*sqrt(2))

            // --- k-net: this role's ks/kv contracted with mq ---
            const float* wk = s_w[0][el];
            float contrib = 0.0f;
            if (role < 8) {
                int o = role;
                float ks = 0.0f;
                #pragma unroll
                for (int i = 0; i < 8; i++)
                    ks += a[i] * wk[i * 8 + o] + b[i] * wk[64 + i * 8 + o];
                contrib = s_mq[p][el][o] * (ks * nrm);
            } else {
                int o = role - 8;
                #pragma unroll
                for (int c = 0; c < 3; c++) {
                    float uk = 0.0f, tk = 0.0f;
                    #pragma unroll
                    for (int i = 0; i < 8; i++) {
                        uk += a[i] * wk[128 + i * 8 + o];
                        tk = fmaf(s_g[p][el][8 + i * 3 + c], wk[192 + i * 8 + o], tk);
                    }
                    float kv_c = nrm * (s_s1[p][el][c] * uk + tk);
                    contrib = fmaf(s_mq[p][el][8 + 3 * o + c], kv_c, contrib);
                }
            }
            contrib += __shfl_xor(contrib, 1);
            contrib += __shfl_xor(contrib, 2);
            contrib += __shfl_xor(contrib, 4);
            contrib += __shfl_xor(contrib, 8);
            if (role == 0) logits[e] = contrib * 0.08838834764831845f; // 1/(8*sqrt(2))

            // --- v-net TP -> vout ---
            const float* wv = s_w[1][el];
            if (role < 8) {
                int o = role;
                float vs = 0.0f;
                #pragma unroll
                for (int i = 0; i < 8; i++)
                    vs += a[i] * wv[i * 8 + o] + b[i] * wv[64 + i * 8 + o];
                vout[(size_t)e * 32 + o] = vs * nrm;
            } else {
                int o = role - 8;
                #pragma unroll
                for (int c = 0; c < 3; c++) {
                    float uv = 0.0f, tv = 0.0f;
                    #pragma unroll
                    for (int i = 0; i < 8; i++) {
                        uv += a[i] * wv[128 + i * 8 + o];
                        tv = fmaf(s_g[p][el][8 + i * 3 + c], wv[192 + i * 8 + o], tv);
                    }
                    vout[(size_t)e * 32 + 8 + o * 3 + c] = nrm * (s_s1[p][el][c] * uv + tv);
                }
            }
        }
        // no trailing barrier: next group writes the other gather buffer;
        // s_hb/s_w writes of group g+1 are fenced by barriers 1 and 2.
    }
}

// ---------------------------------------------------------------------------
// out_kernel: one half-wave (32 lanes) per node (proven, fp32 v).
// ---------------------------------------------------------------------------
__global__ __launch_bounds__(256) void out_kernel(
    const float* __restrict__ logits, const float* __restrict__ cutoff,
    const float* __restrict__ v, float* __restrict__ out)
{
    int t = threadIdx.x, wave = t >> 6, lane = t & 63;
    int half = lane >> 5, hl = lane & 31;
    int n = blockIdx.x * 8 + wave * 2 + half;

    float lg = -INFINITY, cw = 0.0f;
    if (hl < DEG) {
        lg = logits[(size_t)n * DEG + hl];
        cw = cutoff[(size_t)n * DEG + hl];
    }
    float mx = lg;
    mx = fmaxf(mx, __shfl_xor(mx, 16));
    mx = fmaxf(mx, __shfl_xor(mx, 8));
    mx = fmaxf(mx, __shfl_xor(mx, 4));
    mx = fmaxf(mx, __shfl_xor(mx, 2));
    mx = fmaxf(mx, __shfl_xor(mx, 1));

    float ew = cw * __expf(lg - mx);
    float z = ew;
    z += __shfl_xor(z, 16);
    z += __shfl_xor(z, 8);
    z += __shfl_xor(z, 4);
    z += __shfl_xor(z, 2);
    z += __shfl_xor(z, 1);
    z = (z == 0.0f) ? 1.0f : z;
    float coef = sqrtf(ew / z + 1e-12f);

    float acc = 0.0f;
    int base = half * 32;
    #pragma unroll
    for (int ee = 0; ee < DEG; ee++) {
        float ce = __shfl(coef, base + ee);
        acc = fmaf(ce, v[((size_t)n * DEG + ee) * 32 + hl], acc);
    }
    out[(size_t)n * 32 + hl] = acc;
}

// ---------------------------------------------------------------------------
extern "C" void kernel_launch(void* const* d_in, const int* in_sizes, int n_in,
                              void* d_out, int out_size, void* d_ws, size_t ws_size,
                              hipStream_t stream) {
    const float* f    = (const float*)d_in[0];
    const float* pos  = (const float*)d_in[1];
    const float* Wqs  = (const float*)d_in[2];
    const float* Wqv  = (const float*)d_in[3];
    const float* Wk1  = (const float*)d_in[4];
    const float* Wk2  = (const float*)d_in[5];
    const float* Wv1  = (const float*)d_in[6];
    const float* Wv2  = (const float*)d_in[7];
    const float* Wds  = (const float*)d_in[8];
    const float* Wdv  = (const float*)d_in[9];
    const int* esrc   = (const int*)d_in[10];
    const int* edst   = (const int*)d_in[11];
    float* out        = (float*)d_out;

    char* ws = (char*)d_ws;
    uint4* wsB2  = (uint4*)(ws);                       // 65536 B
    float* mqbuf = (float*)(ws + 65536);               // N*32*4 = 2 MB
    float* lbuf  = mqbuf + (size_t)NN * 32;            // E
    float* cbuf  = lbuf + (size_t)EE;                  // E
    float* vbuf  = cbuf + (size_t)EE;                  // E*32

    prep_kernel<<<dim3(16 + (NN * 32) / 256), dim3(256), 0, stream>>>(
        f, Wqs, Wqv, Wk2, Wv2, Wds, Wdv, wsB2, mqbuf);
    edge_kernel<<<dim3(EE / (16 * NG)), dim3(256), 0, stream>>>(
        f, pos, Wk1, Wv1, esrc, edst, mqbuf, wsB2, lbuf, cbuf, vbuf);
    out_kernel<<<dim3(NN / 8), dim3(256), 0, stream>>>(lbuf, cbuf, vbuf, out);
}